// Round 1
// baseline (858.748 us; speedup 1.0000x reference)
//
#include <hip/hip_runtime.h>

#define N_NODES 100000
#define E_EDGES 1600000
#define IN_C 128
#define HID_C 64
#define OUT_C 32

// ---- degree: deg[dst] += 1 over real edges (self-loop added in dinv pass) ----
__global__ void deg_kernel(const int* __restrict__ dst, float* __restrict__ deg) {
    int e = blockIdx.x * blockDim.x + threadIdx.x;
    if (e < E_EDGES) atomicAdd(&deg[dst[e]], 1.0f);
}

// ---- dinv[i] = rsqrt(deg[i] + 1)  (in place; deg+1 > 0 always) ----
__global__ void dinv_kernel(float* __restrict__ deg) {
    int i = blockIdx.x * blockDim.x + threadIdx.x;
    if (i < N_NODES) deg[i] = rsqrtf(deg[i] + 1.0f);
}

// ---- hs[i][c] = dinv[i] * (x @ W1)[i][c], W1 staged in LDS (32 KB) ----
__global__ void gemm1_kernel(const float* __restrict__ x, const float* __restrict__ W1,
                             const float* __restrict__ dinv, float* __restrict__ hs) {
    __shared__ float sW[IN_C * HID_C];
    for (int i = threadIdx.x; i < IN_C * HID_C; i += 256) sW[i] = W1[i];
    __syncthreads();
    const int c = threadIdx.x & 63;                 // wave-contiguous: LDS 2-way alias = free
    const int row = blockIdx.x * 4 + (threadIdx.x >> 6);
    if (row >= N_NODES) return;
    const float4* xr = (const float4*)(x + row * IN_C);  // wave-uniform addr -> 1 txn/load
    float acc = 0.f;
#pragma unroll
    for (int k4 = 0; k4 < IN_C / 4; ++k4) {
        float4 xv = xr[k4];
        acc = fmaf(xv.x, sW[(k4 * 4 + 0) * HID_C + c], acc);
        acc = fmaf(xv.y, sW[(k4 * 4 + 1) * HID_C + c], acc);
        acc = fmaf(xv.z, sW[(k4 * 4 + 2) * HID_C + c], acc);
        acc = fmaf(xv.w, sW[(k4 * 4 + 3) * HID_C + c], acc);
    }
    hs[row * HID_C + c] = acc * dinv[row];
}

// ---- agg[dst] += hs[src] : one wave per edge (64 ch), coalesced gather + atomic scatter ----
__global__ void scatter1_kernel(const int* __restrict__ src, const int* __restrict__ dst,
                                const float* __restrict__ hs, float* __restrict__ agg) {
    int t = blockIdx.x * blockDim.x + threadIdx.x;
    int e = t >> 6, c = t & 63;
    atomicAdd(&agg[dst[e] * HID_C + c], hs[src[e] * HID_C + c]);
}

// ---- h2 = relu(dinv*(agg + hs_self) + b1), written in place into agg ----
__global__ void finalize1_kernel(float* __restrict__ agg, const float* __restrict__ hs,
                                 const float* __restrict__ dinv, const float* __restrict__ b1) {
    int t = blockIdx.x * blockDim.x + threadIdx.x;
    if (t < N_NODES * HID_C) {
        int row = t >> 6, c = t & 63;
        float v = dinv[row] * (agg[t] + hs[t]) + b1[c];
        agg[t] = v > 0.f ? v : 0.f;
    }
}

// ---- gs[i][c] = dinv[i] * (h2 @ W2)[i][c], W2 staged in LDS (8 KB) ----
__global__ void gemm2_kernel(const float* __restrict__ h2, const float* __restrict__ W2,
                             const float* __restrict__ dinv, float* __restrict__ gs) {
    __shared__ float sW[HID_C * OUT_C];
    for (int i = threadIdx.x; i < HID_C * OUT_C; i += 256) sW[i] = W2[i];
    __syncthreads();
    const int c = threadIdx.x & 31;
    const int row = blockIdx.x * 8 + (threadIdx.x >> 5);
    if (row >= N_NODES) return;
    const float4* hr = (const float4*)(h2 + row * HID_C);
    float acc = 0.f;
#pragma unroll
    for (int k4 = 0; k4 < HID_C / 4; ++k4) {
        float4 hv = hr[k4];
        acc = fmaf(hv.x, sW[(k4 * 4 + 0) * OUT_C + c], acc);
        acc = fmaf(hv.y, sW[(k4 * 4 + 1) * OUT_C + c], acc);
        acc = fmaf(hv.z, sW[(k4 * 4 + 2) * OUT_C + c], acc);
        acc = fmaf(hv.w, sW[(k4 * 4 + 3) * OUT_C + c], acc);
    }
    gs[row * OUT_C + c] = acc * dinv[row];
}

// ---- out[dst] += gs[src] : 2 edges per wave (32 ch) ----
__global__ void scatter2_kernel(const int* __restrict__ src, const int* __restrict__ dst,
                                const float* __restrict__ gs, float* __restrict__ out) {
    int t = blockIdx.x * blockDim.x + threadIdx.x;
    int e = t >> 5, c = t & 31;
    atomicAdd(&out[dst[e] * OUT_C + c], gs[src[e] * OUT_C + c]);
}

// ---- out = dinv*(out + gs_self) + b2 ----
__global__ void finalize2_kernel(float* __restrict__ out, const float* __restrict__ gs,
                                 const float* __restrict__ dinv, const float* __restrict__ b2) {
    int t = blockIdx.x * blockDim.x + threadIdx.x;
    if (t < N_NODES * OUT_C) {
        int row = t >> 5, c = t & 31;
        out[t] = dinv[row] * (out[t] + gs[t]) + b2[c];
    }
}

extern "C" void kernel_launch(void* const* d_in, const int* in_sizes, int n_in,
                              void* d_out, int out_size, void* d_ws, size_t ws_size,
                              hipStream_t stream) {
    const float* x  = (const float*)d_in[0];   // [N,128]
    const int*   ei = (const int*)d_in[1];     // [2,E]
    const float* W1 = (const float*)d_in[2];   // [128,64]
    const float* b1 = (const float*)d_in[3];   // [64]
    const float* W2 = (const float*)d_in[4];   // [64,32]
    const float* b2 = (const float*)d_in[5];   // [32]
    float* out = (float*)d_out;                // [N,32]

    const int* srcv = ei;
    const int* dstv = ei + E_EDGES;

    float* ws   = (float*)d_ws;
    float* dinv = ws;                               // N floats (deg, then dinv in place)
    float* hs   = ws + N_NODES;                     // N*64 (layer1 scaled h; reused as gs)
    float* agg  = ws + N_NODES + N_NODES * HID_C;   // N*64 (layer1 accum, then h2 in place)

    // zero the accumulators (ws/out are poisoned 0xAA before every call)
    hipMemsetAsync(dinv, 0, N_NODES * sizeof(float), stream);
    hipMemsetAsync(agg,  0, N_NODES * HID_C * sizeof(float), stream);
    hipMemsetAsync(out,  0, N_NODES * OUT_C * sizeof(float), stream);

    deg_kernel<<<(E_EDGES + 255) / 256, 256, 0, stream>>>(dstv, dinv);
    dinv_kernel<<<(N_NODES + 255) / 256, 256, 0, stream>>>(dinv);

    gemm1_kernel<<<N_NODES / 4, 256, 0, stream>>>(x, W1, dinv, hs);
    scatter1_kernel<<<(E_EDGES * 64) / 256, 256, 0, stream>>>(srcv, dstv, hs, agg);
    finalize1_kernel<<<(N_NODES * HID_C + 255) / 256, 256, 0, stream>>>(agg, hs, dinv, b1);

    gemm2_kernel<<<N_NODES / 8, 256, 0, stream>>>(agg, W2, dinv, hs);  // gs -> hs buffer
    scatter2_kernel<<<(E_EDGES * 32) / 256, 256, 0, stream>>>(srcv, dstv, hs, out);
    finalize2_kernel<<<(N_NODES * OUT_C + 255) / 256, 256, 0, stream>>>(out, hs, dinv, b2);
}

// Round 2
// 586.687 us; speedup vs baseline: 1.4637x; 1.4637x over previous
//
#include <hip/hip_runtime.h>

#define N_NODES 100000
#define E_EDGES 1600000
#define IN_C 128
#define HID_C 64
#define OUT_C 32
#define SCAN_B 256
#define SCAN_NB ((N_NODES + SCAN_B - 1) / SCAN_B)   // 391 blocks <= 512

// ---- degree count: deg[dst]++ over real edges (int atomics, L2-resident) ----
__global__ void count_kernel(const int* __restrict__ dst, int* __restrict__ deg) {
    int e = blockIdx.x * blockDim.x + threadIdx.x;
    if (e < E_EDGES) atomicAdd(&deg[dst[e]], 1);
}

// ---- dinv[i] = rsqrt(deg[i] + 1)  (self-loop folded in) ----
__global__ void dinv_kernel(const int* __restrict__ deg, float* __restrict__ dinv) {
    int i = blockIdx.x * blockDim.x + threadIdx.x;
    if (i < N_NODES) dinv[i] = rsqrtf((float)deg[i] + 1.0f);
}

// ---- scan stage 1: per-block exclusive scan of deg -> row_ptr, block sums -> bsums ----
__global__ void scan1_kernel(const int* __restrict__ deg, int* __restrict__ row_ptr,
                             int* __restrict__ bsums) {
    __shared__ int s[SCAN_B];
    int i = blockIdx.x * SCAN_B + threadIdx.x;
    int v = (i < N_NODES) ? deg[i] : 0;
    s[threadIdx.x] = v;
    __syncthreads();
    for (int off = 1; off < SCAN_B; off <<= 1) {
        int t = (threadIdx.x >= off) ? s[threadIdx.x - off] : 0;
        __syncthreads();
        s[threadIdx.x] += t;
        __syncthreads();
    }
    if (i < N_NODES) row_ptr[i] = s[threadIdx.x] - v;   // exclusive within block
    if (threadIdx.x == SCAN_B - 1) bsums[blockIdx.x] = s[SCAN_B - 1];
}

// ---- scan stage 2: single-block exclusive scan of the 391 block sums ----
__global__ void scan2_kernel(int* __restrict__ bsums) {
    __shared__ int s[512];
    int v = (threadIdx.x < SCAN_NB) ? bsums[threadIdx.x] : 0;
    s[threadIdx.x] = v;
    __syncthreads();
    for (int off = 1; off < 512; off <<= 1) {
        int t = (threadIdx.x >= off) ? s[threadIdx.x - off] : 0;
        __syncthreads();
        s[threadIdx.x] += t;
        __syncthreads();
    }
    if (threadIdx.x < SCAN_NB) bsums[threadIdx.x] = s[threadIdx.x] - v;
}

// ---- scan stage 3: add block offsets; init cursor; cap row_ptr[N] ----
__global__ void scan3_kernel(int* __restrict__ row_ptr, const int* __restrict__ bsums,
                             int* __restrict__ cursor) {
    int i = blockIdx.x * SCAN_B + threadIdx.x;
    if (i < N_NODES) {
        int v = row_ptr[i] + bsums[blockIdx.x];
        row_ptr[i] = v;
        cursor[i] = v;
    }
    if (i == 0) row_ptr[N_NODES] = E_EDGES;
}

// ---- CSR column fill: col[cursor[dst]++] = src ----
__global__ void build_col_kernel(const int* __restrict__ src, const int* __restrict__ dst,
                                 int* __restrict__ cursor, int* __restrict__ col) {
    int e = blockIdx.x * blockDim.x + threadIdx.x;
    if (e < E_EDGES) {
        int pos = atomicAdd(&cursor[dst[e]], 1);
        col[pos] = src[e];
    }
}

// ---- hs[i][c] = dinv[i] * (x @ W1)[i][c], W1 staged in LDS (32 KB) ----
__global__ void gemm1_kernel(const float* __restrict__ x, const float* __restrict__ W1,
                             const float* __restrict__ dinv, float* __restrict__ hs) {
    __shared__ float sW[IN_C * HID_C];
    for (int i = threadIdx.x; i < IN_C * HID_C; i += 256) sW[i] = W1[i];
    __syncthreads();
    const int c = threadIdx.x & 63;
    const int row = blockIdx.x * 4 + (threadIdx.x >> 6);
    if (row >= N_NODES) return;
    const float4* xr = (const float4*)(x + row * IN_C);
    float acc = 0.f;
#pragma unroll
    for (int k4 = 0; k4 < IN_C / 4; ++k4) {
        float4 xv = xr[k4];
        acc = fmaf(xv.x, sW[(k4 * 4 + 0) * HID_C + c], acc);
        acc = fmaf(xv.y, sW[(k4 * 4 + 1) * HID_C + c], acc);
        acc = fmaf(xv.z, sW[(k4 * 4 + 2) * HID_C + c], acc);
        acc = fmaf(xv.w, sW[(k4 * 4 + 3) * HID_C + c], acc);
    }
    hs[row * HID_C + c] = acc * dinv[row];
}

// ---- layer-1 aggregate: one wave per node, lanes = 64 channels.
//      h2 = relu(dinv*(hs_self + sum_{s in adj} hs[s]) + b1)  — no atomics, 1 write/node ----
__global__ void agg1_kernel(const int* __restrict__ row_ptr, const int* __restrict__ col,
                            const float* __restrict__ hs, const float* __restrict__ dinv,
                            const float* __restrict__ b1, float* __restrict__ h2) {
    const int node = blockIdx.x * 4 + (threadIdx.x >> 6);
    const int c = threadIdx.x & 63;
    if (node >= N_NODES) return;
    const int beg = row_ptr[node], end = row_ptr[node + 1];
    float acc = hs[node * HID_C + c];     // self loop
    int j = beg;
    for (; j + 1 < end; j += 2) {         // 2-way unroll for load ILP
        int s0 = col[j], s1 = col[j + 1];
        float v0 = hs[s0 * HID_C + c];
        float v1 = hs[s1 * HID_C + c];
        acc += v0 + v1;
    }
    if (j < end) acc += hs[col[j] * HID_C + c];
    float v = dinv[node] * acc + b1[c];
    h2[node * HID_C + c] = v > 0.f ? v : 0.f;
}

// ---- gs[i][c] = dinv[i] * (h2 @ W2)[i][c], W2 staged in LDS (8 KB) ----
__global__ void gemm2_kernel(const float* __restrict__ h2, const float* __restrict__ W2,
                             const float* __restrict__ dinv, float* __restrict__ gs) {
    __shared__ float sW[HID_C * OUT_C];
    for (int i = threadIdx.x; i < HID_C * OUT_C; i += 256) sW[i] = W2[i];
    __syncthreads();
    const int c = threadIdx.x & 31;
    const int row = blockIdx.x * 8 + (threadIdx.x >> 5);
    if (row >= N_NODES) return;
    const float4* hr = (const float4*)(h2 + row * HID_C);
    float acc = 0.f;
#pragma unroll
    for (int k4 = 0; k4 < HID_C / 4; ++k4) {
        float4 hv = hr[k4];
        acc = fmaf(hv.x, sW[(k4 * 4 + 0) * OUT_C + c], acc);
        acc = fmaf(hv.y, sW[(k4 * 4 + 1) * OUT_C + c], acc);
        acc = fmaf(hv.z, sW[(k4 * 4 + 2) * OUT_C + c], acc);
        acc = fmaf(hv.w, sW[(k4 * 4 + 3) * OUT_C + c], acc);
    }
    gs[row * OUT_C + c] = acc * dinv[row];
}

// ---- layer-2 aggregate: 32 lanes per node (2 nodes/wave), fused finalize ----
__global__ void agg2_kernel(const int* __restrict__ row_ptr, const int* __restrict__ col,
                            const float* __restrict__ gs, const float* __restrict__ dinv,
                            const float* __restrict__ b2, float* __restrict__ out) {
    const int node = blockIdx.x * 8 + (threadIdx.x >> 5);
    const int c = threadIdx.x & 31;
    if (node >= N_NODES) return;
    const int beg = row_ptr[node], end = row_ptr[node + 1];
    float acc = gs[node * OUT_C + c];     // self loop
    int j = beg;
    for (; j + 1 < end; j += 2) {
        int s0 = col[j], s1 = col[j + 1];
        float v0 = gs[s0 * OUT_C + c];
        float v1 = gs[s1 * OUT_C + c];
        acc += v0 + v1;
    }
    if (j < end) acc += gs[col[j] * OUT_C + c];
    out[node * OUT_C + c] = dinv[node] * acc + b2[c];
}

extern "C" void kernel_launch(void* const* d_in, const int* in_sizes, int n_in,
                              void* d_out, int out_size, void* d_ws, size_t ws_size,
                              hipStream_t stream) {
    const float* x  = (const float*)d_in[0];   // [N,128]
    const int*   ei = (const int*)d_in[1];     // [2,E]
    const float* W1 = (const float*)d_in[2];   // [128,64]
    const float* b1 = (const float*)d_in[3];   // [64]
    const float* W2 = (const float*)d_in[4];   // [64,32]
    const float* b2 = (const float*)d_in[5];   // [32]
    float* out = (float*)d_out;                // [N,32]

    const int* srcv = ei;
    const int* dstv = ei + E_EDGES;

    // workspace layout (~59.3 MB)
    float* dinv = (float*)d_ws;                 // N
    float* hs   = dinv + N_NODES;               // N*64  (layer1 scaled h; reused as gs)
    float* h2   = hs + (size_t)N_NODES * HID_C; // N*64
    int* deg     = (int*)(h2 + (size_t)N_NODES * HID_C); // N
    int* bsums   = deg + N_NODES;               // 512
    int* row_ptr = bsums + 512;                 // N+1
    int* cursor  = row_ptr + N_NODES + 1;       // N
    int* col     = cursor + N_NODES;            // E
    float* gs = hs;                             // reuse after agg1

    hipMemsetAsync(deg, 0, N_NODES * sizeof(int), stream);

    // CSR build
    count_kernel<<<(E_EDGES + 255) / 256, 256, 0, stream>>>(dstv, deg);
    dinv_kernel<<<(N_NODES + 255) / 256, 256, 0, stream>>>(deg, dinv);
    scan1_kernel<<<SCAN_NB, SCAN_B, 0, stream>>>(deg, row_ptr, bsums);
    scan2_kernel<<<1, 512, 0, stream>>>(bsums);
    scan3_kernel<<<SCAN_NB, SCAN_B, 0, stream>>>(row_ptr, bsums, cursor);
    build_col_kernel<<<(E_EDGES + 255) / 256, 256, 0, stream>>>(srcv, dstv, cursor, col);

    // layer 1
    gemm1_kernel<<<N_NODES / 4, 256, 0, stream>>>(x, W1, dinv, hs);
    agg1_kernel<<<(N_NODES + 3) / 4, 256, 0, stream>>>(row_ptr, col, hs, dinv, b1, h2);

    // layer 2
    gemm2_kernel<<<N_NODES / 8, 256, 0, stream>>>(h2, W2, dinv, gs);
    agg2_kernel<<<(N_NODES + 7) / 8, 256, 0, stream>>>(row_ptr, col, gs, dinv, b2, out);
}

// Round 3
// 433.238 us; speedup vs baseline: 1.9822x; 1.3542x over previous
//
#include <hip/hip_runtime.h>

#define N_NODES 100000
#define E_EDGES 1600000
#define IN_C 128
#define HID_C 64
#define OUT_C 32
#define SCAN_B 256
#define SCAN_NB ((N_NODES + SCAN_B - 1) / SCAN_B)   // 391 blocks <= 512

// ---- degree count: deg[dst]++ over real edges (int atomics, L2-resident) ----
__global__ void count_kernel(const int* __restrict__ dst, int* __restrict__ deg) {
    int e = blockIdx.x * blockDim.x + threadIdx.x;
    if (e < E_EDGES) atomicAdd(&deg[dst[e]], 1);
}

// ---- dinv[i] = rsqrt(deg[i] + 1)  (self-loop folded in) ----
__global__ void dinv_kernel(const int* __restrict__ deg, float* __restrict__ dinv) {
    int i = blockIdx.x * blockDim.x + threadIdx.x;
    if (i < N_NODES) dinv[i] = rsqrtf((float)deg[i] + 1.0f);
}

// ---- scan stage 1: per-block exclusive scan of deg -> row_ptr, block sums -> bsums ----
__global__ void scan1_kernel(const int* __restrict__ deg, int* __restrict__ row_ptr,
                             int* __restrict__ bsums) {
    __shared__ int s[SCAN_B];
    int i = blockIdx.x * SCAN_B + threadIdx.x;
    int v = (i < N_NODES) ? deg[i] : 0;
    s[threadIdx.x] = v;
    __syncthreads();
    for (int off = 1; off < SCAN_B; off <<= 1) {
        int t = (threadIdx.x >= off) ? s[threadIdx.x - off] : 0;
        __syncthreads();
        s[threadIdx.x] += t;
        __syncthreads();
    }
    if (i < N_NODES) row_ptr[i] = s[threadIdx.x] - v;   // exclusive within block
    if (threadIdx.x == SCAN_B - 1) bsums[blockIdx.x] = s[SCAN_B - 1];
}

// ---- scan stage 2: single-block exclusive scan of the 391 block sums ----
__global__ void scan2_kernel(int* __restrict__ bsums) {
    __shared__ int s[512];
    int v = (threadIdx.x < SCAN_NB) ? bsums[threadIdx.x] : 0;
    s[threadIdx.x] = v;
    __syncthreads();
    for (int off = 1; off < 512; off <<= 1) {
        int t = (threadIdx.x >= off) ? s[threadIdx.x - off] : 0;
        __syncthreads();
        s[threadIdx.x] += t;
        __syncthreads();
    }
    if (threadIdx.x < SCAN_NB) bsums[threadIdx.x] = s[threadIdx.x] - v;
}

// ---- scan stage 3: add block offsets; init cursor; cap row_ptr[N] ----
__global__ void scan3_kernel(int* __restrict__ row_ptr, const int* __restrict__ bsums,
                             int* __restrict__ cursor) {
    int i = blockIdx.x * SCAN_B + threadIdx.x;
    if (i < N_NODES) {
        int v = row_ptr[i] + bsums[blockIdx.x];
        row_ptr[i] = v;
        cursor[i] = v;
    }
    if (i == 0) row_ptr[N_NODES] = E_EDGES;
}

// ---- CSR column fill: col[cursor[dst]++] = src ----
__global__ void build_col_kernel(const int* __restrict__ src, const int* __restrict__ dst,
                                 int* __restrict__ cursor, int* __restrict__ col) {
    int e = blockIdx.x * blockDim.x + threadIdx.x;
    if (e < E_EDGES) {
        int pos = atomicAdd(&cursor[dst[e]], 1);
        col[pos] = src[e];
    }
}

// ---- hs = dinv[row] * (x @ W1) : register-tiled 4 rows x 8 cols per thread ----
// block 256 threads -> 128 rows/block; W1 (32 KB) in LDS [k][c]
__global__ __launch_bounds__(256) void gemm1_kernel(const float* __restrict__ x,
                                                    const float* __restrict__ W1,
                                                    const float* __restrict__ dinv,
                                                    float* __restrict__ hs) {
    __shared__ float sW[IN_C * HID_C];
    for (int i = threadIdx.x; i < IN_C * HID_C; i += 256) sW[i] = W1[i];
    __syncthreads();
    const int cg = (threadIdx.x & 7) * 8;                       // 8 cols/thread
    const int row0 = blockIdx.x * 128 + (threadIdx.x >> 3) * 4; // 4 rows/thread
    float acc[4][8];
#pragma unroll
    for (int r = 0; r < 4; ++r)
#pragma unroll
        for (int c = 0; c < 8; ++c) acc[r][c] = 0.f;

    int rr[4];
#pragma unroll
    for (int r = 0; r < 4; ++r) rr[r] = min(row0 + r, N_NODES - 1);  // clamp tail loads

    const float4* x4 = (const float4*)x;
#pragma unroll 2
    for (int k4 = 0; k4 < IN_C / 4; ++k4) {
        float4 xv[4];
#pragma unroll
        for (int r = 0; r < 4; ++r) xv[r] = x4[(size_t)rr[r] * (IN_C / 4) + k4];
        float xs[4][4];
#pragma unroll
        for (int r = 0; r < 4; ++r) {
            xs[r][0] = xv[r].x; xs[r][1] = xv[r].y; xs[r][2] = xv[r].z; xs[r][3] = xv[r].w;
        }
#pragma unroll
        for (int kk = 0; kk < 4; ++kk) {
            const float4* wp = (const float4*)(sW + (k4 * 4 + kk) * HID_C + cg);
            float4 w0 = wp[0], w1 = wp[1];
            float wv[8] = {w0.x, w0.y, w0.z, w0.w, w1.x, w1.y, w1.z, w1.w};
#pragma unroll
            for (int r = 0; r < 4; ++r)
#pragma unroll
                for (int c = 0; c < 8; ++c)
                    acc[r][c] = fmaf(xs[r][kk], wv[c], acc[r][c]);
        }
    }
#pragma unroll
    for (int r = 0; r < 4; ++r) {
        int row = row0 + r;
        if (row < N_NODES) {
            float dv = dinv[row];
            float4 o0, o1;
            o0.x = acc[r][0] * dv; o0.y = acc[r][1] * dv; o0.z = acc[r][2] * dv; o0.w = acc[r][3] * dv;
            o1.x = acc[r][4] * dv; o1.y = acc[r][5] * dv; o1.z = acc[r][6] * dv; o1.w = acc[r][7] * dv;
            float4* op = (float4*)(hs + (size_t)row * HID_C + cg);
            op[0] = o0; op[1] = o1;
        }
    }
}

// ---- layer-1 aggregate: one wave per node, lanes = 64 channels, 4-way unroll ----
__global__ void agg1_kernel(const int* __restrict__ row_ptr, const int* __restrict__ col,
                            const float* __restrict__ hs, const float* __restrict__ dinv,
                            const float* __restrict__ b1, float* __restrict__ h2) {
    const int node = blockIdx.x * 4 + (threadIdx.x >> 6);
    const int c = threadIdx.x & 63;
    if (node >= N_NODES) return;
    const int beg = row_ptr[node], end = row_ptr[node + 1];
    float acc = hs[node * HID_C + c];     // self loop
    int j = beg;
    for (; j + 3 < end; j += 4) {
        int s0 = col[j], s1 = col[j + 1], s2 = col[j + 2], s3 = col[j + 3];
        float v0 = hs[s0 * HID_C + c];
        float v1 = hs[s1 * HID_C + c];
        float v2 = hs[s2 * HID_C + c];
        float v3 = hs[s3 * HID_C + c];
        acc += (v0 + v1) + (v2 + v3);
    }
    for (; j < end; ++j) acc += hs[col[j] * HID_C + c];
    float v = dinv[node] * acc + b1[c];
    h2[node * HID_C + c] = v > 0.f ? v : 0.f;
}

// ---- gs = dinv[row] * (h2 @ W2) : register-tiled 2 rows x 8 cols per thread ----
// block 256 -> 128 rows/block; W2 (8 KB) in LDS
__global__ __launch_bounds__(256) void gemm2_kernel(const float* __restrict__ h2,
                                                    const float* __restrict__ W2,
                                                    const float* __restrict__ dinv,
                                                    float* __restrict__ gs) {
    __shared__ float sW[HID_C * OUT_C];
    for (int i = threadIdx.x; i < HID_C * OUT_C; i += 256) sW[i] = W2[i];
    __syncthreads();
    const int cg = (threadIdx.x & 3) * 8;                       // 8 cols/thread (32 total)
    const int row0 = blockIdx.x * 128 + (threadIdx.x >> 2) * 2; // 2 rows/thread
    float acc[2][8];
#pragma unroll
    for (int r = 0; r < 2; ++r)
#pragma unroll
        for (int c = 0; c < 8; ++c) acc[r][c] = 0.f;

    int rr[2];
#pragma unroll
    for (int r = 0; r < 2; ++r) rr[r] = min(row0 + r, N_NODES - 1);

    const float4* h4 = (const float4*)h2;
#pragma unroll 2
    for (int k4 = 0; k4 < HID_C / 4; ++k4) {
        float4 xv[2];
#pragma unroll
        for (int r = 0; r < 2; ++r) xv[r] = h4[(size_t)rr[r] * (HID_C / 4) + k4];
        float xs[2][4];
#pragma unroll
        for (int r = 0; r < 2; ++r) {
            xs[r][0] = xv[r].x; xs[r][1] = xv[r].y; xs[r][2] = xv[r].z; xs[r][3] = xv[r].w;
        }
#pragma unroll
        for (int kk = 0; kk < 4; ++kk) {
            const float4* wp = (const float4*)(sW + (k4 * 4 + kk) * OUT_C + cg);
            float4 w0 = wp[0], w1 = wp[1];
            float wv[8] = {w0.x, w0.y, w0.z, w0.w, w1.x, w1.y, w1.z, w1.w};
#pragma unroll
            for (int r = 0; r < 2; ++r)
#pragma unroll
                for (int c = 0; c < 8; ++c)
                    acc[r][c] = fmaf(xs[r][kk], wv[c], acc[r][c]);
        }
    }
#pragma unroll
    for (int r = 0; r < 2; ++r) {
        int row = row0 + r;
        if (row < N_NODES) {
            float dv = dinv[row];
            float4 o0, o1;
            o0.x = acc[r][0] * dv; o0.y = acc[r][1] * dv; o0.z = acc[r][2] * dv; o0.w = acc[r][3] * dv;
            o1.x = acc[r][4] * dv; o1.y = acc[r][5] * dv; o1.z = acc[r][6] * dv; o1.w = acc[r][7] * dv;
            float4* op = (float4*)(gs + (size_t)row * OUT_C + cg);
            op[0] = o0; op[1] = o1;
        }
    }
}

// ---- layer-2 aggregate: 32 lanes per node (2 nodes/wave), fused finalize, 4-way unroll ----
__global__ void agg2_kernel(const int* __restrict__ row_ptr, const int* __restrict__ col,
                            const float* __restrict__ gs, const float* __restrict__ dinv,
                            const float* __restrict__ b2, float* __restrict__ out) {
    const int node = blockIdx.x * 8 + (threadIdx.x >> 5);
    const int c = threadIdx.x & 31;
    if (node >= N_NODES) return;
    const int beg = row_ptr[node], end = row_ptr[node + 1];
    float acc = gs[node * OUT_C + c];     // self loop
    int j = beg;
    for (; j + 3 < end; j += 4) {
        int s0 = col[j], s1 = col[j + 1], s2 = col[j + 2], s3 = col[j + 3];
        float v0 = gs[s0 * OUT_C + c];
        float v1 = gs[s1 * OUT_C + c];
        float v2 = gs[s2 * OUT_C + c];
        float v3 = gs[s3 * OUT_C + c];
        acc += (v0 + v1) + (v2 + v3);
    }
    for (; j < end; ++j) acc += gs[col[j] * OUT_C + c];
    out[node * OUT_C + c] = dinv[node] * acc + b2[c];
}

extern "C" void kernel_launch(void* const* d_in, const int* in_sizes, int n_in,
                              void* d_out, int out_size, void* d_ws, size_t ws_size,
                              hipStream_t stream) {
    const float* x  = (const float*)d_in[0];   // [N,128]
    const int*   ei = (const int*)d_in[1];     // [2,E]
    const float* W1 = (const float*)d_in[2];   // [128,64]
    const float* b1 = (const float*)d_in[3];   // [64]
    const float* W2 = (const float*)d_in[4];   // [64,32]
    const float* b2 = (const float*)d_in[5];   // [32]
    float* out = (float*)d_out;                // [N,32]

    const int* srcv = ei;
    const int* dstv = ei + E_EDGES;

    // workspace layout (~59.3 MB)
    float* dinv = (float*)d_ws;                 // N
    float* hs   = dinv + N_NODES;               // N*64  (layer1 scaled h; reused as gs)
    float* h2   = hs + (size_t)N_NODES * HID_C; // N*64
    int* deg     = (int*)(h2 + (size_t)N_NODES * HID_C); // N
    int* bsums   = deg + N_NODES;               // 512
    int* row_ptr = bsums + 512;                 // N+1
    int* cursor  = row_ptr + N_NODES + 1;       // N
    int* col     = cursor + N_NODES;            // E
    float* gs = hs;                             // reuse after agg1

    hipMemsetAsync(deg, 0, N_NODES * sizeof(int), stream);

    // CSR build
    count_kernel<<<(E_EDGES + 255) / 256, 256, 0, stream>>>(dstv, deg);
    dinv_kernel<<<(N_NODES + 255) / 256, 256, 0, stream>>>(deg, dinv);
    scan1_kernel<<<SCAN_NB, SCAN_B, 0, stream>>>(deg, row_ptr, bsums);
    scan2_kernel<<<1, 512, 0, stream>>>(bsums);
    scan3_kernel<<<SCAN_NB, SCAN_B, 0, stream>>>(row_ptr, bsums, cursor);
    build_col_kernel<<<(E_EDGES + 255) / 256, 256, 0, stream>>>(srcv, dstv, cursor, col);

    // layer 1
    gemm1_kernel<<<(N_NODES + 127) / 128, 256, 0, stream>>>(x, W1, dinv, hs);
    agg1_kernel<<<(N_NODES + 3) / 4, 256, 0, stream>>>(row_ptr, col, hs, dinv, b1, h2);

    // layer 2
    gemm2_kernel<<<(N_NODES + 127) / 128, 256, 0, stream>>>(h2, W2, dinv, gs);
    agg2_kernel<<<(N_NODES + 7) / 8, 256, 0, stream>>>(row_ptr, col, gs, dinv, b2, out);
}